// Round 1
// baseline (102.107 us; speedup 1.0000x reference)
//
#include <hip/hip_runtime.h>

#define BATCH 2
#define CCH   256
#define WDIM  64
#define HW    4096   // 64*64
#define KWIN  49

// ---------------------------------------------------------------------------
// Kernel 1: bilinear warp of f2 by c1 (zero padding, align_corners) fused with
// transpose of both f2w and f1 into channel-last [B, HW, C] layout.
// grid = (B * HW/64, C/64) = (128, 4), block = 256.
// Each block: 64 pixels x 64 channels.  LDS 64x65 padded tiles (stride 65 ->
// bank = lane + const, conflict-free).
// ---------------------------------------------------------------------------
__global__ __launch_bounds__(256) void warp_transpose_kernel(
    const float* __restrict__ f1, const float* __restrict__ f2,
    const float* __restrict__ c1, float* __restrict__ f1t,
    float* __restrict__ f2wt)
{
    __shared__ float s1[64][65];
    __shared__ float s2[64][65];

    const int b  = blockIdx.x >> 6;          // 64 blocks per batch
    const int nb = (blockIdx.x & 63) << 6;   // pixel base
    const int cc = blockIdx.y << 6;          // channel base
    const int t   = threadIdx.x;
    const int pix = t & 63;                  // lane = pixel (coalesced n)
    const int tq  = t >> 6;                  // wave id 0..3
    const int n   = nb + pix;

    // per-pixel warp coords/weights (computed once per thread)
    const float cx = c1[(b * 2 + 0) * HW + n];
    const float cy = c1[(b * 2 + 1) * HW + n];
    const float x0f = floorf(cx), y0f = floorf(cy);
    const float fx = cx - x0f, fy = cy - y0f;
    const int ix0 = (int)x0f, iy0 = (int)y0f;
    const int ix1 = ix0 + 1,  iy1 = iy0 + 1;

    float w00 = (1.f - fx) * (1.f - fy);
    float w01 = fx * (1.f - fy);
    float w10 = (1.f - fx) * fy;
    float w11 = fx * fy;
    // zero-padding: kill weights of out-of-bounds corners
    if (ix0 < 0 || ix0 >= WDIM) { w00 = 0.f; w10 = 0.f; }
    if (ix1 < 0 || ix1 >= WDIM) { w01 = 0.f; w11 = 0.f; }
    if (iy0 < 0 || iy0 >= WDIM) { w00 = 0.f; w01 = 0.f; }
    if (iy1 < 0 || iy1 >= WDIM) { w10 = 0.f; w11 = 0.f; }
    const int xc0 = min(max(ix0, 0), WDIM - 1);
    const int xc1 = min(max(ix1, 0), WDIM - 1);
    const int yc0 = min(max(iy0, 0), WDIM - 1);
    const int yc1 = min(max(iy1, 0), WDIM - 1);
    const int o00 = yc0 * WDIM + xc0, o01 = yc0 * WDIM + xc1;
    const int o10 = yc1 * WDIM + xc0, o11 = yc1 * WDIM + xc1;

    const float* f2b = f2 + ((size_t)b * CCH + cc) * HW;
    const float* f1b = f1 + ((size_t)b * CCH + cc) * HW;

    // phase A: gather-warp f2 + coalesced read f1, write LDS [c][pix]
    #pragma unroll
    for (int j = 0; j < 16; ++j) {
        const int cl = tq * 16 + j;              // local channel 0..63
        const float* p2 = f2b + (size_t)cl * HW;
        s2[cl][pix] = w00 * p2[o00] + w01 * p2[o01] +
                      w10 * p2[o10] + w11 * p2[o11];
        s1[cl][pix] = f1b[(size_t)cl * HW + n];
    }
    __syncthreads();

    // phase B: write out channel-last, 256B coalesced stores per wave
    const int cl2 = t & 63;                      // lane = channel
    #pragma unroll
    for (int j = 0; j < 16; ++j) {
        const int pix2 = j * 4 + tq;
        const size_t base = ((size_t)(b * HW + nb + pix2)) * CCH + cc + cl2;
        f1t[base]  = s1[cl2][pix2];
        f2wt[base] = s2[cl2][pix2];
    }
}

// ---------------------------------------------------------------------------
// Kernel 2: correlation. One wave per pixel; lane = one of 64 window
// positions (8x8 integer grid around floor(c0)-3). Each lane does a
// 256-float dot product (float4, contiguous per lane thanks to channel-last
// layout). Then 4 __shfl's pick the bilinear corners for each of the 49 taps.
// grid = B*HW/4 = 2048 blocks, block = 256 (4 waves = 4 pixels).
// ---------------------------------------------------------------------------
__global__ __launch_bounds__(256) void corr_kernel(
    const float* __restrict__ f1t, const float* __restrict__ f2wt,
    const float* __restrict__ c0, float* __restrict__ outc)
{
    const int t    = threadIdx.x;
    const int lane = t & 63;
    const int wv   = t >> 6;
    const int pg   = blockIdx.x * 4 + wv;   // global pixel 0..8191
    const int b    = pg >> 12;
    const int n    = pg & 4095;

    const float cx = c0[(b * 2 + 0) * HW + n];
    const float cy = c0[(b * 2 + 1) * HW + n];
    const float x0f = floorf(cx), y0f = floorf(cy);
    const float fx = cx - x0f, fy = cy - y0f;
    const int bx = (int)x0f - 3, by = (int)y0f - 3;

    const int ix = lane & 7, iy = lane >> 3;
    const int px = bx + ix,  py = by + iy;
    const bool valid = (px >= 0) && (px < WDIM) && (py >= 0) && (py < WDIM);

    float acc = 0.f;
    if (valid) {
        const float4* pw = (const float4*)(f2wt + ((size_t)(b * HW + py * WDIM + px)) * CCH);
        const float4* pq = (const float4*)(f1t  + ((size_t)(b * HW + n)) * CCH);
        #pragma unroll 8
        for (int i = 0; i < CCH / 4; ++i) {
            const float4 a = pq[i];
            const float4 v = pw[i];
            acc += a.x * v.x + a.y * v.y + a.z * v.z + a.w * v.w;
        }
    }

    // combine 8x8 dot grid -> 49 outputs (lanes 0..48)
    const int k   = lane;
    const int dyi = (k < KWIN) ? (k / 7) : 0;
    const int dxi = (k < KWIN) ? (k % 7) : 0;
    const int s   = dyi * 8 + dxi;
    const float d00 = __shfl(acc, s,     64);
    const float d01 = __shfl(acc, s + 1, 64);
    const float d10 = __shfl(acc, s + 8, 64);
    const float d11 = __shfl(acc, s + 9, 64);

    if (k < KWIN) {
        const float w00 = (1.f - fx) * (1.f - fy);
        const float w01 = fx * (1.f - fy);
        const float w10 = (1.f - fx) * fy;
        const float w11 = fx * fy;
        const float r = (w00 * d00 + w01 * d01 + w10 * d10 + w11 * d11) * 0.0625f;
        outc[(size_t)(b * KWIN + k) * HW + n] = r;
    }
}

extern "C" void kernel_launch(void* const* d_in, const int* in_sizes, int n_in,
                              void* d_out, int out_size, void* d_ws, size_t ws_size,
                              hipStream_t stream) {
    (void)in_sizes; (void)n_in; (void)out_size; (void)ws_size;
    const float* f1 = (const float*)d_in[0];
    const float* f2 = (const float*)d_in[1];
    const float* c1 = (const float*)d_in[2];
    const float* c0 = (const float*)d_in[3];
    float* out = (float*)d_out;

    float* f1t  = (float*)d_ws;                      // [B,HW,C] 8 MB
    float* f2wt = f1t + (size_t)BATCH * HW * CCH;    // [B,HW,C] 8 MB

    // output 0: c1 passthrough (16384 floats)
    hipMemcpyAsync(out, (const void*)c1, (size_t)BATCH * 2 * HW * sizeof(float),
                   hipMemcpyDeviceToDevice, stream);

    dim3 g1(BATCH * (HW / 64), CCH / 64);
    warp_transpose_kernel<<<g1, 256, 0, stream>>>(f1, f2, c1, f1t, f2wt);

    corr_kernel<<<(BATCH * HW) / 4, 256, 0, stream>>>(f1t, f2wt, c0, out + BATCH * 2 * HW);
}

// Round 2
// 36.581 us; speedup vs baseline: 2.7912x; 2.7912x over previous
//
#include <hip/hip_runtime.h>
#include <hip/hip_bf16.h>

#define BATCH 2
#define CCH   256
#define WDIM  64
#define HW    4096   // 64*64
#define KWIN  49

// ---------------------------------------------------------------------------
// Kernel 1: bilinear warp of f2 by c1 (zero padding) fused with transpose of
// both f2w and f1 into channel-last bf16 [B, HW, C] layout.
// grid = (B * HW/64, C/64) = (128, 4), block = 256.
// LDS 64x65 padded fp32 tiles (stride 65 -> conflict-free); bf16 convert at
// the store (single RNE rounding after fp32 bilinear).
// ---------------------------------------------------------------------------
__global__ __launch_bounds__(256) void warp_transpose_kernel(
    const float* __restrict__ f1, const float* __restrict__ f2,
    const float* __restrict__ c1, __hip_bfloat16* __restrict__ f1t,
    __hip_bfloat16* __restrict__ f2wt)
{
    __shared__ float s1[64][65];
    __shared__ float s2[64][65];

    const int b  = blockIdx.x >> 6;          // 64 blocks per batch
    const int nb = (blockIdx.x & 63) << 6;   // pixel base
    const int cc = blockIdx.y << 6;          // channel base
    const int t   = threadIdx.x;
    const int pix = t & 63;                  // lane = pixel (coalesced n)
    const int tq  = t >> 6;                  // wave id 0..3
    const int n   = nb + pix;

    const float cx = c1[(b * 2 + 0) * HW + n];
    const float cy = c1[(b * 2 + 1) * HW + n];
    const float x0f = floorf(cx), y0f = floorf(cy);
    const float fx = cx - x0f, fy = cy - y0f;
    const int ix0 = (int)x0f, iy0 = (int)y0f;
    const int ix1 = ix0 + 1,  iy1 = iy0 + 1;

    float w00 = (1.f - fx) * (1.f - fy);
    float w01 = fx * (1.f - fy);
    float w10 = (1.f - fx) * fy;
    float w11 = fx * fy;
    if (ix0 < 0 || ix0 >= WDIM) { w00 = 0.f; w10 = 0.f; }
    if (ix1 < 0 || ix1 >= WDIM) { w01 = 0.f; w11 = 0.f; }
    if (iy0 < 0 || iy0 >= WDIM) { w00 = 0.f; w01 = 0.f; }
    if (iy1 < 0 || iy1 >= WDIM) { w10 = 0.f; w11 = 0.f; }
    const int xc0 = min(max(ix0, 0), WDIM - 1);
    const int xc1 = min(max(ix1, 0), WDIM - 1);
    const int yc0 = min(max(iy0, 0), WDIM - 1);
    const int yc1 = min(max(iy1, 0), WDIM - 1);
    const int o00 = yc0 * WDIM + xc0, o01 = yc0 * WDIM + xc1;
    const int o10 = yc1 * WDIM + xc0, o11 = yc1 * WDIM + xc1;

    const float* f2b = f2 + ((size_t)b * CCH + cc) * HW;
    const float* f1b = f1 + ((size_t)b * CCH + cc) * HW;

    #pragma unroll
    for (int j = 0; j < 16; ++j) {
        const int cl = tq * 16 + j;              // local channel 0..63
        const float* p2 = f2b + (size_t)cl * HW;
        s2[cl][pix] = w00 * p2[o00] + w01 * p2[o01] +
                      w10 * p2[o10] + w11 * p2[o11];
        s1[cl][pix] = f1b[(size_t)cl * HW + n];
    }
    __syncthreads();

    // channel-last bf16 stores: per wave-instr 64 consecutive ushorts (128B)
    const int cl2 = t & 63;                      // lane = channel
    #pragma unroll
    for (int j = 0; j < 16; ++j) {
        const int pix2 = j * 4 + tq;
        const size_t base = ((size_t)(b * HW + nb + pix2)) * CCH + cc + cl2;
        f1t[base]  = __float2bfloat16(s1[cl2][pix2]);
        f2wt[base] = __float2bfloat16(s2[cl2][pix2]);
    }
}

__device__ __forceinline__ void unpack8(uint4 u, float* f) {
    f[0] = __uint_as_float(u.x << 16);
    f[1] = __uint_as_float(u.x & 0xffff0000u);
    f[2] = __uint_as_float(u.y << 16);
    f[3] = __uint_as_float(u.y & 0xffff0000u);
    f[4] = __uint_as_float(u.z << 16);
    f[5] = __uint_as_float(u.z & 0xffff0000u);
    f[6] = __uint_as_float(u.w << 16);
    f[7] = __uint_as_float(u.w & 0xffff0000u);
}

// ---------------------------------------------------------------------------
// Kernel 2: correlation. One wave per pixel. Lane split: g = lane>>3 = window
// column (ix), j = lane&7 = 64-channel chunk. For each window row o (=iy),
// the 8 lanes of group g read one contiguous 128B line per instruction
// (8 lines/wave-instr total vs 64 before). Group-dot reduced via 3 shfl_xor,
// redistributed through per-wave LDS (no barrier: single-wave producer/
// consumer), then 49 bilinear-combined outputs.
// grid = B*HW/4 = 2048 blocks, block = 256 (4 waves = 4 pixels).
// ---------------------------------------------------------------------------
__global__ __launch_bounds__(256) void corr_kernel(
    const __hip_bfloat16* __restrict__ f1t,
    const __hip_bfloat16* __restrict__ f2wt,
    const float* __restrict__ c0, float* __restrict__ outc)
{
    __shared__ float sD[4][64];

    const int t    = threadIdx.x;
    const int lane = t & 63;
    const int wv   = t >> 6;
    const int j    = lane & 7;    // channel chunk (8 bf16 x 4 iters = 32 ch)
    const int g    = lane >> 3;   // window column ix

    // XCD-aware bijective swizzle: 2048 = 8 * 256
    const int bid = blockIdx.x;
    const int swz = (bid & 7) * 256 + (bid >> 3);
    const int pg  = swz * 4 + wv;            // global pixel 0..8191
    const int b   = pg >> 12;
    const int n   = pg & 4095;

    const float cx = c0[(b * 2 + 0) * HW + n];
    const float cy = c0[(b * 2 + 1) * HW + n];
    const float x0f = floorf(cx), y0f = floorf(cy);
    const float fx = cx - x0f, fy = cy - y0f;
    const int bx = (int)x0f - 3, by = (int)y0f - 3;

    // q: unpack this lane's 32 channels once (channels i*64 + j*8 .. +7)
    const ushort* q = (const ushort*)(f1t + ((size_t)(b * HW + n)) * CCH);
    float qf[32];
    #pragma unroll
    for (int i = 0; i < 4; ++i) {
        uint4 u = *(const uint4*)(q + i * 64 + j * 8);
        unpack8(u, qf + i * 8);
    }

    const int px = bx + g;
    const bool pxok = (px >= 0) && (px < WDIM);
    const ushort* wbase = (const ushort*)(f2wt + ((size_t)b * HW) * CCH);

    #pragma unroll
    for (int o = 0; o < 8; ++o) {
        const int py = by + o;
        float a = 0.f;
        if (pxok && py >= 0 && py < WDIM) {
            const ushort* wrow = wbase + ((size_t)(py * WDIM + px)) * CCH;
            #pragma unroll
            for (int i = 0; i < 4; ++i) {
                uint4 u = *(const uint4*)(wrow + i * 64 + j * 8);
                float wf[8];
                unpack8(u, wf);
                #pragma unroll
                for (int e = 0; e < 8; ++e) a += qf[i * 8 + e] * wf[e];
            }
        }
        // reduce over the 8 lanes of this group (contiguous lanes)
        a += __shfl_xor(a, 1, 64);
        a += __shfl_xor(a, 2, 64);
        a += __shfl_xor(a, 4, 64);
        if (j == 0) sD[wv][o * 8 + g] = a;   // D[iy=o][ix=g]
    }
    // same-wave producer/consumer: lockstep, compiler inserts lgkmcnt waits

    const int k = lane;
    if (k < KWIN) {
        const int dyi = k / 7;
        const int dxi = k % 7;
        const int s   = dyi * 8 + dxi;
        const float d00 = sD[wv][s];
        const float d01 = sD[wv][s + 1];
        const float d10 = sD[wv][s + 8];
        const float d11 = sD[wv][s + 9];
        const float w00 = (1.f - fx) * (1.f - fy);
        const float w01 = fx * (1.f - fy);
        const float w10 = (1.f - fx) * fy;
        const float w11 = fx * fy;
        const float r = (w00 * d00 + w01 * d01 + w10 * d10 + w11 * d11) * 0.0625f;
        outc[(size_t)(b * KWIN + k) * HW + n] = r;
    }
}

extern "C" void kernel_launch(void* const* d_in, const int* in_sizes, int n_in,
                              void* d_out, int out_size, void* d_ws, size_t ws_size,
                              hipStream_t stream) {
    (void)in_sizes; (void)n_in; (void)out_size; (void)ws_size;
    const float* f1 = (const float*)d_in[0];
    const float* f2 = (const float*)d_in[1];
    const float* c1 = (const float*)d_in[2];
    const float* c0 = (const float*)d_in[3];
    float* out = (float*)d_out;

    __hip_bfloat16* f1t  = (__hip_bfloat16*)d_ws;                 // [B,HW,C] 4 MB
    __hip_bfloat16* f2wt = f1t + (size_t)BATCH * HW * CCH;        // [B,HW,C] 4 MB

    // output 0: c1 passthrough (16384 floats)
    hipMemcpyAsync(out, (const void*)c1, (size_t)BATCH * 2 * HW * sizeof(float),
                   hipMemcpyDeviceToDevice, stream);

    dim3 g1(BATCH * (HW / 64), CCH / 64);
    warp_transpose_kernel<<<g1, 256, 0, stream>>>(f1, f2, c1, f1t, f2wt);

    corr_kernel<<<(BATCH * HW) / 4, 256, 0, stream>>>(f1t, f2wt, c0, out + BATCH * 2 * HW);
}

// Round 3
// 31.215 us; speedup vs baseline: 3.2711x; 1.1719x over previous
//
#include <hip/hip_runtime.h>
#include <hip/hip_fp16.h>

#define BATCH 2
#define CCH   256
#define WDIM  64
#define HW    4096   // 64*64
#define KWIN  49

__device__ __forceinline__ __half2 u2h2(unsigned u) {
    union { unsigned u; __half2 h; } v; v.u = u; return v.h;
}
__device__ __forceinline__ unsigned h22u(__half2 h) {
    union { unsigned u; __half2 h; } v; v.h = h; return v.u;
}

// ---------------------------------------------------------------------------
// Kernel 1: bilinear warp of f2 by c1 (zero padding) fused with transpose of
// both f2w and f1 into channel-last f16 [B, HW, C] layout, plus the c1
// passthrough copy (output 0).
// grid = (B * HW/64, C/64) = (128, 4), block = 256.
// LDS 64x65 padded fp32 tiles: phase-A writes lane=pixel (stride-65 ->
// conflict-free), phase-B reads 4 rows/lane (2-way alias = free).
// ---------------------------------------------------------------------------
__global__ __launch_bounds__(256) void warp_transpose_kernel(
    const float* __restrict__ f1, const float* __restrict__ f2,
    const float* __restrict__ c1, __half* __restrict__ f1t,
    __half* __restrict__ f2wt, float* __restrict__ out0)
{
    __shared__ float s1[64][65];
    __shared__ float s2[64][65];

    const int t  = threadIdx.x;
    const int b  = blockIdx.x >> 6;          // 64 blocks per batch
    const int nb = (blockIdx.x & 63) << 6;   // pixel base
    const int cc = blockIdx.y << 6;          // channel base

    // output 0: c1 passthrough (16384 floats over 128 x-blocks)
    if (cc == 0 && t < 128) {
        const int idx = blockIdx.x * 128 + t;
        out0[idx] = c1[idx];
    }

    const int pix = t & 63;                  // lane = pixel (coalesced n)
    const int tq  = t >> 6;                  // wave id 0..3
    const int n   = nb + pix;

    const float cx = c1[(b * 2 + 0) * HW + n];
    const float cy = c1[(b * 2 + 1) * HW + n];
    const float x0f = floorf(cx), y0f = floorf(cy);
    const float fx = cx - x0f, fy = cy - y0f;
    const int ix0 = (int)x0f, iy0 = (int)y0f;
    const int ix1 = ix0 + 1,  iy1 = iy0 + 1;

    float w00 = (1.f - fx) * (1.f - fy);
    float w01 = fx * (1.f - fy);
    float w10 = (1.f - fx) * fy;
    float w11 = fx * fy;
    if (ix0 < 0 || ix0 >= WDIM) { w00 = 0.f; w10 = 0.f; }
    if (ix1 < 0 || ix1 >= WDIM) { w01 = 0.f; w11 = 0.f; }
    if (iy0 < 0 || iy0 >= WDIM) { w00 = 0.f; w01 = 0.f; }
    if (iy1 < 0 || iy1 >= WDIM) { w10 = 0.f; w11 = 0.f; }
    const int xc0 = min(max(ix0, 0), WDIM - 1);
    const int xc1 = min(max(ix1, 0), WDIM - 1);
    const int yc0 = min(max(iy0, 0), WDIM - 1);
    const int yc1 = min(max(iy1, 0), WDIM - 1);
    const int o00 = yc0 * WDIM + xc0, o01 = yc0 * WDIM + xc1;
    const int o10 = yc1 * WDIM + xc0, o11 = yc1 * WDIM + xc1;

    const float* f2b = f2 + ((size_t)b * CCH + cc) * HW;
    const float* f1b = f1 + ((size_t)b * CCH + cc) * HW;

    #pragma unroll
    for (int j = 0; j < 16; ++j) {
        const int cl = tq * 16 + j;              // local channel 0..63
        const float* p2 = f2b + (size_t)cl * HW;
        s2[cl][pix] = w00 * p2[o00] + w01 * p2[o01] +
                      w10 * p2[o10] + w11 * p2[o11];
        s1[cl][pix] = f1b[(size_t)cl * HW + n];
    }
    __syncthreads();

    // phase B: lane packs 4 consecutive channels of one pixel -> uint2 store
    const int lo = t & 15;                       // channel quad: 4*lo..+3
    const int pq = t >> 4;                       // 0..15
    ushort* o1 = (ushort*)f1t;
    ushort* o2 = (ushort*)f2wt;
    #pragma unroll
    for (int j = 0; j < 4; ++j) {
        const int pix2 = j * 16 + pq;
        const size_t base = ((size_t)(b * HW + nb + pix2)) * CCH + cc + 4 * lo;
        const int c4 = 4 * lo;
        uint2 va, vb;
        va.x = h22u(__halves2half2(__float2half(s1[c4 + 0][pix2]),
                                   __float2half(s1[c4 + 1][pix2])));
        va.y = h22u(__halves2half2(__float2half(s1[c4 + 2][pix2]),
                                   __float2half(s1[c4 + 3][pix2])));
        vb.x = h22u(__halves2half2(__float2half(s2[c4 + 0][pix2]),
                                   __float2half(s2[c4 + 1][pix2])));
        vb.y = h22u(__halves2half2(__float2half(s2[c4 + 2][pix2]),
                                   __float2half(s2[c4 + 3][pix2])));
        *(uint2*)(o1 + base) = va;
        *(uint2*)(o2 + base) = vb;
    }
}

// ---------------------------------------------------------------------------
// Kernel 2: correlation. One wave per pixel. Lane split: g = lane>>3 = window
// column (ix), j = lane&7 = channel chunk. Per window row: 4 uint4 loads
// (8 cache lines/instr across groups) + 16 packed v_pk_fma_f16 into two
// half2 chains, fp32 combine, 3 shfl_xor group reduce, LDS redistribute,
// 49 bilinear-combined outputs.
// grid = B*HW/4 = 2048 blocks, block = 256 (4 waves = 4 pixels).
// ---------------------------------------------------------------------------
__global__ __launch_bounds__(256) void corr_kernel(
    const __half* __restrict__ f1t,
    const __half* __restrict__ f2wt,
    const float* __restrict__ c0, float* __restrict__ outc)
{
    __shared__ float sD[4][64];

    const int t    = threadIdx.x;
    const int lane = t & 63;
    const int wv   = t >> 6;
    const int j    = lane & 7;    // channel chunk
    const int g    = lane >> 3;   // window column ix

    // XCD-aware bijective swizzle: 2048 = 8 * 256
    const int bid = blockIdx.x;
    const int swz = (bid & 7) * 256 + (bid >> 3);
    const int pg  = swz * 4 + wv;            // global pixel 0..8191
    const int b   = pg >> 12;
    const int n   = pg & 4095;

    const float cx = c0[(b * 2 + 0) * HW + n];
    const float cy = c0[(b * 2 + 1) * HW + n];
    const float x0f = floorf(cx), y0f = floorf(cy);
    const float fx = cx - x0f, fy = cy - y0f;
    const int bx = (int)x0f - 3, by = (int)y0f - 3;

    // q: this lane's 32 channels (i*64 + j*8 .. +7), kept packed as half2
    const ushort* q = (const ushort*)f1t + ((size_t)(b * HW + n)) * CCH;
    __half2 qh[16];
    #pragma unroll
    for (int i = 0; i < 4; ++i) {
        uint4 u = *(const uint4*)(q + i * 64 + j * 8);
        qh[i * 4 + 0] = u2h2(u.x);
        qh[i * 4 + 1] = u2h2(u.y);
        qh[i * 4 + 2] = u2h2(u.z);
        qh[i * 4 + 3] = u2h2(u.w);
    }

    const int px = bx + g;
    const bool pxok = (px >= 0) && (px < WDIM);
    const ushort* wbase = (const ushort*)f2wt + ((size_t)b * HW) * CCH;

    #pragma unroll
    for (int o = 0; o < 8; ++o) {
        const int py = by + o;
        float a = 0.f;
        if (pxok && py >= 0 && py < WDIM) {
            const ushort* wrow = wbase + ((size_t)(py * WDIM + px)) * CCH;
            __half2 acc0 = __halves2half2(__float2half(0.f), __float2half(0.f));
            __half2 acc1 = acc0;
            #pragma unroll
            for (int i = 0; i < 4; ++i) {
                uint4 u = *(const uint4*)(wrow + i * 64 + j * 8);
                acc0 = __hfma2(qh[i * 4 + 0], u2h2(u.x), acc0);
                acc1 = __hfma2(qh[i * 4 + 1], u2h2(u.y), acc1);
                acc0 = __hfma2(qh[i * 4 + 2], u2h2(u.z), acc0);
                acc1 = __hfma2(qh[i * 4 + 3], u2h2(u.w), acc1);
            }
            const __half2 s = __hadd2(acc0, acc1);
            a = __low2float(s) + __high2float(s);
        }
        a += __shfl_xor(a, 1, 64);
        a += __shfl_xor(a, 2, 64);
        a += __shfl_xor(a, 4, 64);
        if (j == 0) sD[wv][o * 8 + g] = a;   // D[iy=o][ix=g]
    }
    // same-wave producer/consumer: DS ops issue in program order

    const int k = lane;
    if (k < KWIN) {
        const int dyi = k / 7;
        const int dxi = k % 7;
        const int s   = dyi * 8 + dxi;
        const float d00 = sD[wv][s];
        const float d01 = sD[wv][s + 1];
        const float d10 = sD[wv][s + 8];
        const float d11 = sD[wv][s + 9];
        const float w00 = (1.f - fx) * (1.f - fy);
        const float w01 = fx * (1.f - fy);
        const float w10 = (1.f - fx) * fy;
        const float w11 = fx * fy;
        const float r = (w00 * d00 + w01 * d01 + w10 * d10 + w11 * d11) * 0.0625f;
        outc[(size_t)(b * KWIN + k) * HW + n] = r;
    }
}

extern "C" void kernel_launch(void* const* d_in, const int* in_sizes, int n_in,
                              void* d_out, int out_size, void* d_ws, size_t ws_size,
                              hipStream_t stream) {
    (void)in_sizes; (void)n_in; (void)out_size; (void)ws_size;
    const float* f1 = (const float*)d_in[0];
    const float* f2 = (const float*)d_in[1];
    const float* c1 = (const float*)d_in[2];
    const float* c0 = (const float*)d_in[3];
    float* out = (float*)d_out;

    __half* f1t  = (__half*)d_ws;                     // [B,HW,C] 4 MB
    __half* f2wt = f1t + (size_t)BATCH * HW * CCH;    // [B,HW,C] 4 MB

    dim3 g1(BATCH * (HW / 64), CCH / 64);
    warp_transpose_kernel<<<g1, 256, 0, stream>>>(f1, f2, c1, f1t, f2wt, out);

    corr_kernel<<<(BATCH * HW) / 4, 256, 0, stream>>>(f1t, f2wt, c0, out + BATCH * 2 * HW);
}